// Round 1
// baseline (3354.539 us; speedup 1.0000x reference)
//
#include <hip/hip_runtime.h>
#include <stdint.h>

#define Tn 100
#define Dn 51
#define Hn 128
#define G4 512     // 4*H
#define BR 8       // batch rows per workgroup
#define NWG 256    // workgroups (2048 / 8)
#define NTH 1024   // 16 waves
#define RP 264     // xhA row stride in bf16 elems (16B-aligned rows)

typedef unsigned int uint32;
typedef unsigned short u16;
typedef short s16x8 __attribute__((ext_vector_type(8)));   // 8 bf16 = 4 VGPRs
typedef float f32x4v __attribute__((ext_vector_type(4)));

__device__ __forceinline__ float rcp_(float x){ return __builtin_amdgcn_rcpf(x); }
__device__ __forceinline__ float sigm(float x){ return rcp_(1.f + __expf(-x)); }
__device__ __forceinline__ float tanh_(float x){ return 1.f - 2.f*rcp_(1.f + __expf(2.f*x)); }

// fp32 -> bf16 round-to-nearest-even
__device__ __forceinline__ u16 f2bf(float f){
  uint32 u = __float_as_uint(f);
  return (u16)((u + 0x7fffu + ((u >> 16) & 1u)) >> 16);
}
__device__ __forceinline__ float bf2f(u16 u){ return __uint_as_float(((uint32)u)<<16); }

// A-fragment trick: row r (0..7) = bf16-hi of xh row r; row r+8 = bf16-lo.
// One MFMA computes both pumps; epilogue sums D[r] + D[r+8] via shfl.
__device__ __forceinline__ void wr_xh(u16* __restrict__ xhA, int r, int k, float v){
  u16 h = f2bf(v);
  xhA[r*RP + k]     = h;
  xhA[(r+8)*RP + k] = f2bf(v - bf2f(h));
}

struct WP {
  const float* W[6];   // [4H, din]  enc0..2, dec0..2 (fp32)
  const float* U[6];   // [4H, H]
  const float* Bb[6];  // [4H]
  const float* fW;     // [D, H]
  const float* fb;     // [D]
};

// ws: wsw = MFMA-B-fragment-swizzled bf16 weights.
// Layout per layer (uniform 131072 u16): block (n,s) at ((n*8+s)*64+lane)*8+j,
// holding Wc[k = s*32+(lane>>4)*8+j][c = n*16+(lane&15)], Wc = [Wih | Whh] along k,
// zero-padded (k>=K or s>=S). A wave's B-frag load = contiguous 1KB dwordx4.
#define PREP_TOTAL (6*131072 + 6*512 + 8192 + 64)
__global__ void prep_kernel(WP p, u16* __restrict__ wsw, float* __restrict__ bias,
                            float* __restrict__ fwt, float* __restrict__ fbw)
{
  int gid = blockIdx.x*256 + threadIdx.x;
  if (gid >= PREP_TOTAL) return;
  if (gid < 6*131072){
    int l = gid >> 17;
    int e = gid & 131071;
    int n    = e >> 12;
    int s    = (e >> 9) & 7;
    int lane = (e >> 3) & 63;
    int j    = e & 7;
    int k = s*32 + (lane >> 4)*8 + j;
    int c = n*16 + (lane & 15);
    int din = (l % 3 == 0) ? Dn : Hn;
    int K = din + Hn;
    u16 v = 0;
    if (k < K){
      float f = (k < din) ? p.W[l][(size_t)c*din + k] : p.U[l][(size_t)c*Hn + (k - din)];
      v = f2bf(f);
    }
    wsw[gid] = v;
  } else if (gid < 6*131072 + 6*512){
    int i = gid - 6*131072;
    bias[i] = p.Bb[i>>9][i & 511];
  } else if (gid < 6*131072 + 6*512 + 8192){
    int i = gid - (6*131072 + 6*512);
    int k = i >> 6, d = i & 63;
    fwt[i] = (d < Dn) ? p.fW[(size_t)d*Hn + k] : 0.f;
  } else {
    int d = gid - (6*131072 + 6*512 + 8192);
    fbw[d] = (d < Dn) ? p.fb[d] : 0.f;
  }
}

// LDS-only barrier: drain DS ops + barrier, but leave global->VGPR loads (the
// weight stream) in flight. __syncthreads() emits s_waitcnt vmcnt(0) before
// s_barrier and would kill the cross-phase weight prefetch (m97/m201 evidence).
// All cross-thread data in this kernel lives in LDS, so lgkmcnt(0) is the
// only required producer-side drain; 'out' stores are never read in-kernel.
__device__ __forceinline__ void bar_lds(){
  asm volatile("s_waitcnt lgkmcnt(0)" ::: "memory");
  __builtin_amdgcn_s_barrier();
  asm volatile("" ::: "memory");
}

// Prime the per-wave register frag buffer (wave w owns N-tiles 2w, 2w+1).
template<int S>
__device__ __forceinline__ void ld_frags(const u16* __restrict__ wsl, s16x8* bf, int tid){
  const int wave = tid >> 6, lane = tid & 63;
  const u16* bp = wsl + wave*2*4096 + lane*8;
  #pragma unroll
  for (int s=0; s<S; s++){
    bf[2*s]   = *(const s16x8*)(bp + s*512);
    bf[2*s+1] = *(const s16x8*)(bp + 4096 + s*512);
  }
}

// gates[r][c] = biasS[c] + sum_k xh[r][k]*Wc[k][c] via mfma_f32_16x16x32_bf16,
// using B-frags already resident in bf[] — AND per-s reload of bf[] with the
// NEXT layer's frags (per-s so the old/new live ranges overlap by only one
// slot; keeps frag pressure at 64 VGPRs). The reloads are fire-and-forget
// global loads that stay in flight across the following raw barriers and are
// absorbed by counted vmcnt waits at the next gemm — this is the whole point.
// C/D: col=lane&15, row=(lane>>4)*4+reg (m89) -> row r in lane L<32, r+8 in L+32.
template<int S, int SN>
__device__ __forceinline__ void gemm_step(s16x8* bf, const u16* __restrict__ wsn,
                                          const float* __restrict__ blS,
                                          const u16* __restrict__ xh,
                                          float* __restrict__ gates, int tid)
{
  const int wave = tid >> 6, lane = tid & 63;
  const int mrow = lane & 15, kgrp = lane >> 4;
  const int n0 = wave*2;
  const u16* np = wsn + n0*4096 + lane*8;
  const int aoff = mrow*RP + kgrp*8;
  f32x4v acc0 = {0.f,0.f,0.f,0.f}, acc1 = {0.f,0.f,0.f,0.f};
  constexpr int SM = (S > SN) ? S : SN;
  #pragma unroll
  for (int s=0; s<SM; s++){
    if (s < S){
      s16x8 a = *(const s16x8*)(xh + aoff + s*32);
      acc0 = __builtin_amdgcn_mfma_f32_16x16x32_bf16(a, bf[2*s],   acc0, 0, 0, 0);
      acc1 = __builtin_amdgcn_mfma_f32_16x16x32_bf16(a, bf[2*s+1], acc1, 0, 0, 0);
    }
    if (s < SN){
      bf[2*s]   = *(const s16x8*)(np + s*512);
      bf[2*s+1] = *(const s16x8*)(np + 4096 + s*512);
    }
  }
  // fold lo-product rows (8-15, lanes +32) into hi rows (0-7, lanes 0-31)
  #pragma unroll
  for (int v=0; v<4; v++){
    float l0 = __shfl_down(acc0[v], 32);
    float l1 = __shfl_down(acc1[v], 32);
    acc0[v] += l0;
    acc1[v] += l1;
  }
  if (kgrp < 2){
    int rb = kgrp*4;
    int c0g = n0*16 + mrow, c1g = c0g + 16;
    float bv0 = blS[c0g], bv1 = blS[c1g];
    #pragma unroll
    for (int v=0; v<4; v++){
      gates[(rb+v)*G4 + c0g] = acc0[v] + bv0;
      gates[(rb+v)*G4 + c1g] = acc1[v] + bv1;
    }
  }
}

// Fused activation: gates -> (h,c), AND write h straight into the A-tiles that
// consume it (replaces the old build_* phases + a barrier per layer-step):
//   - xh_self[r][din_self + j] : this layer's own gemm at t+1 (recurrent h)
//   - xh_next[r][j]            : next layer's gemm at this t (input x)
__device__ __forceinline__ void activate2(const float* __restrict__ gates,
                                          float* __restrict__ h, float* __restrict__ c,
                                          u16* __restrict__ xh_self, int din_self,
                                          u16* __restrict__ xh_next, int tid)
{
  int r = tid >> 7, j = tid & 127;       // 1024 threads = 8 rows x 128
  const float* g = gates + r*G4;
  float ig = sigm (g[j]);
  float fg = sigm (g[j + Hn]);
  float gg = tanh_(g[j + 2*Hn]);
  float og = sigm (g[j + 3*Hn]);
  int hi = r*Hn + j;
  float cn = fg*c[hi] + ig*gg;
  c[hi] = cn;
  float hv = og*tanh_(cn);
  h[hi] = hv;
  wr_xh(xh_self, r, din_self + j, hv);
  if (xh_next) wr_xh(xh_next, r, j, hv);
}

// src(t) prefetch into 2 registers, issued one layer-step early (and BEFORE the
// next frag stream in program order, so its consumption is a counted vmcnt that
// does not drain the frag loads).
__device__ __forceinline__ void ld_src(const float* __restrict__ src, long b0, int t,
                                       int tid, float& sA, float& sB)
{
  int k = tid & 255;
  if (k < Dn){
    int r0 = tid >> 8;
    sA = src[((size_t)(b0+r0)*Tn + t)*Dn + k];
    sB = src[((size_t)(b0+r0+4)*Tn + t)*Dn + k];
  }
}
__device__ __forceinline__ void st_src(u16* __restrict__ xh0, int tid, float sA, float sB)
{
  int k = tid & 255;
  if (k < Dn){
    int r0 = tid >> 8;
    wr_xh(xh0, r0,   k, sA);
    wr_xh(xh0, r0+4, k, sB);
  }
}

// OUTPUT IS FP32. 8 rows x 64 cols = 512 work items. fwt/fbw read from LDS
// (no VMEM loads here — a global fwt read would drain the d0 frag prefetch).
// pred feeds straight into xh0's x-part for the next decoder step.
__device__ __forceinline__ void proj_out(const float* __restrict__ h2,
                                         const float* __restrict__ fwtS,
                                         const float* __restrict__ fbwS,
                                         u16* __restrict__ xh0,
                                         float* __restrict__ out, long b0, int t, int tid)
{
  if (tid < 512){
    int r = tid >> 6, d = tid & 63;
    const float* h = h2 + r*Hn;
    float acc = 0.f;
    #pragma unroll 8
    for (int k=0;k<Hn;k++) acc += h[k] * fwtS[k*64 + d];
    if (d < Dn){
      float pv = acc + fbwS[d];
      out[((size_t)(b0+r)*Tn + (Tn-1-t))*Dn + d] = pv;
      wr_xh(xh0, r, d, pv);
    }
  }
}

// (1024, 4): 4 waves/EU -> VGPR cap 128. Frag buffer bf[16] = 64 VGPRs; total
// must stay <= 128 (watch VGPR_Count; a spill here is a hard regression).
// Grid is 1 WG/CU; default 2-block targeting caused R9's 10.3 GB spill storm.
__global__ __launch_bounds__(NTH, 4) void lstm_kernel(
    const float* __restrict__ src, const u16* __restrict__ wsw,
    const float* __restrict__ bias, const float* __restrict__ fwt,
    const float* __restrict__ fbw, float* __restrict__ out)
{
  __shared__ __align__(16) u16   xhA[3*16*RP];    // 24.75 KB: per-layer A-tiles
  __shared__ __align__(16) float gates[BR*G4];    // 16 KB
  __shared__ __align__(16) float hS[3*BR*Hn];     // 12 KB
  __shared__ __align__(16) float cS[3*BR*Hn];     // 12 KB
  __shared__ __align__(16) float fwtS[8192];      // 32 KB
  __shared__ __align__(16) float biasS[6*G4];     // 12 KB
  __shared__ __align__(16) float fbwS[64];        // 0.25 KB   (total ~109 KB)

  const int tid = threadIdx.x;
  const long b0 = (long)blockIdx.x * BR;
  u16* xh0 = xhA;
  u16* xh1 = xhA + 16*RP;
  u16* xh2 = xhA + 32*RP;

  const u16* wsE0 = wsw;
  const u16* wsE1 = wsw + 1*131072;
  const u16* wsE2 = wsw + 2*131072;
  const u16* wsD0 = wsw + 3*131072;
  const u16* wsD1 = wsw + 4*131072;
  const u16* wsD2 = wsw + 5*131072;

  s16x8 bf[16];          // per-wave B-frags of the CURRENT layer (64 VGPRs)
  float sA = 0.f, sB = 0.f;

  // ---- init: order matters for counted vmcnt waits ----
  ld_src(src, b0, 0, tid, sA, sB);                 // 2 loads (oldest)
  for (int i=tid; i<8192; i+=NTH) fwtS[i] = fwt[i];   // staged+consumed now
  for (int i=tid; i<6*G4; i+=NTH) biasS[i] = bias[i];
  if (tid < 64) fbwS[tid] = fbw[tid];
  ld_frags<6>(wsE0, bf, tid);                      // e0 stream overlaps init
  for (int i=tid; i<3*16*RP; i+=NTH) xhA[i]=0;     // pads stay 0 forever
  for (int i=tid; i<3*BR*Hn; i+=NTH){ hS[i]=0.f; cS[i]=0.f; }
  bar_lds();
  st_src(xh0, tid, sA, sB);                        // src(0) -> xh0.x
  bar_lds();

  // ---------------- encoder: 2 phases per layer-step ----------------
  for (int t=0;t<Tn;t++){
    gemm_step<6,8>(bf, wsE1, biasS + 0*G4, xh0, gates, tid);
    bar_lds();
    activate2(gates, hS,         cS,         xh0, Dn, xh1, tid);
    bar_lds();
    gemm_step<8,8>(bf, wsE2, biasS + 1*G4, xh1, gates, tid);
    bar_lds();
    activate2(gates, hS + BR*Hn, cS + BR*Hn, xh1, Hn, xh2, tid);
    bar_lds();
    int tn = (t < Tn-1) ? t+1 : Tn-1;
    ld_src(src, b0, tn, tid, sA, sB);              // issued BEFORE next frags
    gemm_step<8,6>(bf, (t < Tn-1) ? wsE0 : wsD0, biasS + 2*G4, xh2, gates, tid);
    bar_lds();
    activate2(gates, hS + 2*BR*Hn, cS + 2*BR*Hn, xh2, Hn, (u16*)nullptr, tid);
    if (t < Tn-1) st_src(xh0, tid, sA, sB);        // src(t+1) -> xh0.x
    bar_lds();
  }

  // ---------------- decoder ----------------
  // xh*.h-parts hold enc-final h (written by enc act at t=99); hS/cS carry the
  // enc-final state. Only xh0.x must be reset to pred(-1)=0.
  {
    int r = tid >> 7, k = tid & 127;
    if (k < Dn){ xh0[r*RP + k] = 0; xh0[(r+8)*RP + k] = 0; }
  }
  bar_lds();

  for (int t=0;t<Tn;t++){
    gemm_step<6,8>(bf, wsD1, biasS + 3*G4, xh0, gates, tid);
    bar_lds();
    activate2(gates, hS,         cS,         xh0, Dn, xh1, tid);
    bar_lds();
    gemm_step<8,8>(bf, wsD2, biasS + 4*G4, xh1, gates, tid);
    bar_lds();
    activate2(gates, hS + BR*Hn, cS + BR*Hn, xh1, Hn, xh2, tid);
    bar_lds();
    gemm_step<8,6>(bf, wsD0, biasS + 5*G4, xh2, gates, tid);   // t=99 reload harmless
    bar_lds();
    activate2(gates, hS + 2*BR*Hn, cS + 2*BR*Hn, xh2, Hn, (u16*)nullptr, tid);
    bar_lds();
    proj_out(hS + 2*BR*Hn, fwtS, fbwS, xh0, out, b0, t, tid);
    bar_lds();
  }
}

extern "C" void kernel_launch(void* const* d_in, const int* in_sizes, int n_in,
                              void* d_out, int out_size, void* d_ws, size_t ws_size,
                              hipStream_t stream)
{
  (void)in_sizes; (void)n_in; (void)out_size; (void)ws_size;
  const float* src = (const float*)d_in[0];
  WP p;
  for (int l=0;l<3;l++){
    p.W[l]    = (const float*)d_in[1  + 3*l];
    p.U[l]    = (const float*)d_in[2  + 3*l];
    p.Bb[l]   = (const float*)d_in[3  + 3*l];
    p.W[3+l]  = (const float*)d_in[10 + 3*l];
    p.U[3+l]  = (const float*)d_in[11 + 3*l];
    p.Bb[3+l] = (const float*)d_in[12 + 3*l];
  }
  p.fW = (const float*)d_in[19];
  p.fb = (const float*)d_in[20];

  // ws: wsw u16[786432] (1.5MB) | bias f32[3072] | fwt f32[8192] | fbw f32[64]
  u16*   wsw  = (u16*)d_ws;
  float* bias = (float*)((char*)d_ws + 6*131072*sizeof(u16));
  float* fwt  = bias + 6*512;
  float* fbw  = fwt + 8192;

  prep_kernel<<<(PREP_TOTAL + 255)/256, 256, 0, stream>>>(p, wsw, bias, fwt, fbw);
  lstm_kernel<<<NWG, NTH, 0, stream>>>(src, wsw, bias, fwt, fbw, (float*)d_out);
}

// Round 2
// 1850.630 us; speedup vs baseline: 1.8126x; 1.8126x over previous
//
#include <hip/hip_runtime.h>
#include <stdint.h>

#define Tn 100
#define Dn 51
#define Hn 128
#define G4 512     // 4*H
#define BR 8       // batch rows per workgroup
#define NWG 256    // workgroups (2048 / 8)
#define NTH 1024   // 16 waves
#define RP 264     // xhA row stride in bf16 elems (16B-aligned rows)

typedef unsigned int uint32;
typedef unsigned short u16;
typedef short s16x8 __attribute__((ext_vector_type(8)));   // 8 bf16 = 4 VGPRs
typedef float f32x4v __attribute__((ext_vector_type(4)));

__device__ __forceinline__ float rcp_(float x){ return __builtin_amdgcn_rcpf(x); }
__device__ __forceinline__ float sigm(float x){ return rcp_(1.f + __expf(-x)); }
__device__ __forceinline__ float tanh_(float x){ return 1.f - 2.f*rcp_(1.f + __expf(2.f*x)); }

// fp32 -> bf16 round-to-nearest-even
__device__ __forceinline__ u16 f2bf(float f){
  uint32 u = __float_as_uint(f);
  return (u16)((u + 0x7fffu + ((u >> 16) & 1u)) >> 16);
}
__device__ __forceinline__ float bf2f(u16 u){ return __uint_as_float(((uint32)u)<<16); }

// A-fragment trick: row r (0..7) = bf16-hi of xh row r; row r+8 = bf16-lo.
// One MFMA computes both pumps; epilogue sums D[r] + D[r+8] via shfl.
__device__ __forceinline__ void wr_xh(u16* __restrict__ xhA, int r, int k, float v){
  u16 h = f2bf(v);
  xhA[r*RP + k]     = h;
  xhA[(r+8)*RP + k] = f2bf(v - bf2f(h));
}

struct WP {
  const float* W[6];   // [4H, din]  enc0..2, dec0..2 (fp32)
  const float* U[6];   // [4H, H]
  const float* Bb[6];  // [4H]
  const float* fW;     // [D, H]
  const float* fb;     // [D]
};

// ws: wsw = MFMA-B-fragment-swizzled bf16 weights.
// Layout per layer (uniform 131072 u16): block (n,s) at ((n*8+s)*64+lane)*8+j,
// holding Wc[k = s*32+(lane>>4)*8+j][c = n*16+(lane&15)], Wc = [Wih | Whh] along k,
// zero-padded (k>=K or s>=S). A wave's B-frag load = contiguous 1KB dwordx4.
#define PREP_TOTAL (6*131072 + 6*512 + 8192 + 64)
__global__ void prep_kernel(WP p, u16* __restrict__ wsw, float* __restrict__ bias,
                            float* __restrict__ fwt, float* __restrict__ fbw)
{
  int gid = blockIdx.x*256 + threadIdx.x;
  if (gid >= PREP_TOTAL) return;
  if (gid < 6*131072){
    int l = gid >> 17;
    int e = gid & 131071;
    int n    = e >> 12;
    int s    = (e >> 9) & 7;
    int lane = (e >> 3) & 63;
    int j    = e & 7;
    int k = s*32 + (lane >> 4)*8 + j;
    int c = n*16 + (lane & 15);
    int din = (l % 3 == 0) ? Dn : Hn;
    int K = din + Hn;
    u16 v = 0;
    if (k < K){
      float f = (k < din) ? p.W[l][(size_t)c*din + k] : p.U[l][(size_t)c*Hn + (k - din)];
      v = f2bf(f);
    }
    wsw[gid] = v;
  } else if (gid < 6*131072 + 6*512){
    int i = gid - 6*131072;
    bias[i] = p.Bb[i>>9][i & 511];
  } else if (gid < 6*131072 + 6*512 + 8192){
    int i = gid - (6*131072 + 6*512);
    int k = i >> 6, d = i & 63;
    fwt[i] = (d < Dn) ? p.fW[(size_t)d*Hn + k] : 0.f;
  } else {
    int d = gid - (6*131072 + 6*512 + 8192);
    fbw[d] = (d < Dn) ? p.fb[d] : 0.f;
  }
}

// gates[r][c] = biasS[c] + sum_k xh[r][k]*Wc[k][c] via mfma_f32_16x16x32_bf16.
// Wave w owns N-tiles n=2w,2w+1. A rows 0-7 = hi, 8-15 = lo (one MFMA/both pumps).
// C/D: col=lane&15, row=(lane>>4)*4+reg (m89) -> row r in lane L<32, r+8 in L+32.
// Weight loads are issued and consumed WITHIN this phase (R1 post-mortem: keeping
// a 64-VGPR frag array live across phases pinned the allocator at the 64-VGPR
// tier and blew FETCH_SIZE up 280x; do not resurrect cross-phase register frags).
// NOTE: unroll 2, NOT full — full unroll (R11) spilled 9.5 GB of scratch.
template<int S>
__device__ __forceinline__ void gemm_mfma(const u16* __restrict__ wsl,
                                          const float* __restrict__ blS,
                                          const u16* __restrict__ xhA,
                                          float* __restrict__ gates, int tid)
{
  const int wave = tid >> 6, lane = tid & 63;
  const int mrow = lane & 15, kgrp = lane >> 4;
  const int n0 = wave*2;
  const u16* bp0 = wsl + n0*4096 + lane*8;
  const int aoff = mrow*RP + kgrp*8;
  f32x4v acc0 = {0.f,0.f,0.f,0.f}, acc1 = {0.f,0.f,0.f,0.f};
  #pragma unroll 2
  for (int s=0; s<S; s++){
    s16x8 a  = *(const s16x8*)(xhA + aoff + s*32);
    s16x8 b0 = *(const s16x8*)(bp0 + s*512);
    s16x8 b1 = *(const s16x8*)(bp0 + 4096 + s*512);
    acc0 = __builtin_amdgcn_mfma_f32_16x16x32_bf16(a, b0, acc0, 0, 0, 0);
    acc1 = __builtin_amdgcn_mfma_f32_16x16x32_bf16(a, b1, acc1, 0, 0, 0);
  }
  // fold lo-product rows (8-15, lanes +32) into hi rows (0-7, lanes 0-31)
  #pragma unroll
  for (int v=0; v<4; v++){
    float l0 = __shfl_down(acc0[v], 32);
    float l1 = __shfl_down(acc1[v], 32);
    acc0[v] += l0;
    acc1[v] += l1;
  }
  if (kgrp < 2){
    int rb = kgrp*4;
    int c0g = n0*16 + mrow, c1g = c0g + 16;
    float bv0 = blS[c0g], bv1 = blS[c1g];
    #pragma unroll
    for (int v=0; v<4; v++){
      gates[(rb+v)*G4 + c0g] = acc0[v] + bv0;
      gates[(rb+v)*G4 + c1g] = acc1[v] + bv1;
    }
  }
}

// Fused activation (replaces the old build_* phases + a barrier per layer-step):
// gates -> (h,c), h written straight into the A-tiles that consume it:
//   - xh_self[r][din_self + j] : this layer's own gemm at t+1 (recurrent h)
//   - xh_next[r][j]            : next layer's gemm at this t (input x)
// hS write only where needed (layer 2, feeds proj).
__device__ __forceinline__ void activate2(const float* __restrict__ gates,
                                          float* __restrict__ h, float* __restrict__ c,
                                          u16* __restrict__ xh_self, int din_self,
                                          u16* __restrict__ xh_next, int tid)
{
  int r = tid >> 7, j = tid & 127;       // 1024 threads = 8 rows x 128
  const float* g = gates + r*G4;
  float ig = sigm (g[j]);
  float fg = sigm (g[j + Hn]);
  float gg = tanh_(g[j + 2*Hn]);
  float og = sigm (g[j + 3*Hn]);
  int hi = r*Hn + j;
  float cn = fg*c[hi] + ig*gg;
  c[hi] = cn;
  float hv = og*tanh_(cn);
  if (h) h[hi] = hv;
  wr_xh(xh_self, r, din_self + j, hv);
  if (xh_next) wr_xh(xh_next, r, j, hv);
}

// src(t+1) prefetch into 2 registers, issued at the START of the layer-0 gemm
// phase (its latency hides under the gemm's own weight stream + MFMAs); stored
// into xh0.x during the following act phase. Drained by the phase barrier.
__device__ __forceinline__ void ld_src(const float* __restrict__ src, long b0, int t,
                                       int tid, float& sA, float& sB)
{
  int k = tid & 255;
  if (k < Dn){
    int r0 = tid >> 8;
    sA = src[((size_t)(b0+r0)*Tn + t)*Dn + k];
    sB = src[((size_t)(b0+r0+4)*Tn + t)*Dn + k];
  }
}
__device__ __forceinline__ void st_src(u16* __restrict__ xh0, int tid, float sA, float sB)
{
  int k = tid & 255;
  if (k < Dn){
    int r0 = tid >> 8;
    wr_xh(xh0, r0,   k, sA);
    wr_xh(xh0, r0+4, k, sB);
  }
}

// OUTPUT IS FP32. 8 rows x 64 cols = 512 work items. fwt/fbw from LDS — the old
// global-fwt path re-read 256 KB per decoder step per WG from L2.
// pred feeds straight into xh0's x-part for the next decoder step.
__device__ __forceinline__ void proj_out(const float* __restrict__ h2,
                                         const float* __restrict__ fwtS,
                                         const float* __restrict__ fbwS,
                                         u16* __restrict__ xh0,
                                         float* __restrict__ out, long b0, int t, int tid)
{
  if (tid < 512){
    int r = tid >> 6, d = tid & 63;
    const float* h = h2 + r*Hn;
    float acc = 0.f;
    #pragma unroll 8
    for (int k=0;k<Hn;k++) acc += h[k] * fwtS[k*64 + d];
    if (d < Dn){
      float pv = acc + fbwS[d];
      out[((size_t)(b0+r)*Tn + (Tn-1-t))*Dn + d] = pv;
      wr_xh(xh0, r, d, pv);
    }
  }
}

// (1024, 4): 4 waves/EU -> VGPR cap 128. Grid is 1 WG/CU; default 2-block
// targeting caused R9's 10.3 GB spill storm. All barriers are __syncthreads()
// (R1's raw-barrier + cross-phase VMEM experiment regressed 63%).
__global__ __launch_bounds__(NTH, 4) void lstm_kernel(
    const float* __restrict__ src, const u16* __restrict__ wsw,
    const float* __restrict__ bias, const float* __restrict__ fwt,
    const float* __restrict__ fbw, float* __restrict__ out)
{
  __shared__ __align__(16) u16   xhA[3*16*RP];    // 24.75 KB: per-layer A-tiles
  __shared__ __align__(16) float gates[BR*G4];    // 16 KB
  __shared__ __align__(16) float hS[BR*Hn];       // 4 KB (layer-2 h only, for proj)
  __shared__ __align__(16) float cS[3*BR*Hn];     // 12 KB
  __shared__ __align__(16) float fwtS[8192];      // 32 KB
  __shared__ __align__(16) float biasS[6*G4];     // 12 KB
  __shared__ __align__(16) float fbwS[64];        // 0.25 KB   (total ~101 KB)

  const int tid = threadIdx.x;
  const long b0 = (long)blockIdx.x * BR;
  u16* xh0 = xhA;
  u16* xh1 = xhA + 16*RP;
  u16* xh2 = xhA + 32*RP;

  float sA = 0.f, sB = 0.f;

  // ---- init ----
  ld_src(src, b0, 0, tid, sA, sB);
  for (int i=tid; i<8192; i+=NTH) fwtS[i] = fwt[i];
  for (int i=tid; i<6*G4; i+=NTH) biasS[i] = bias[i];
  if (tid < 64) fbwS[tid] = fbw[tid];
  for (int i=tid; i<3*16*RP; i+=NTH) xhA[i]=0;     // pads stay 0 forever
  for (int i=tid; i<BR*Hn; i+=NTH)   hS[i]=0.f;
  for (int i=tid; i<3*BR*Hn; i+=NTH) cS[i]=0.f;
  __syncthreads();
  st_src(xh0, tid, sA, sB);                        // src(0) -> xh0.x
  __syncthreads();

  // ---------------- encoder: 6 phases per t (was 9) ----------------
  for (int t=0;t<Tn;t++){
    int tn = (t < Tn-1) ? t+1 : Tn-1;
    ld_src(src, b0, tn, tid, sA, sB);              // hides under gemm0's stream
    gemm_mfma<6>(wsw + 0*131072, biasS + 0*G4, xh0, gates, tid);
    __syncthreads();
    activate2(gates, nullptr, cS,         xh0, Dn, xh1, tid);
    if (t < Tn-1) st_src(xh0, tid, sA, sB);        // src(t+1) -> xh0.x
    __syncthreads();

    gemm_mfma<8>(wsw + 1*131072, biasS + 1*G4, xh1, gates, tid);
    __syncthreads();
    activate2(gates, nullptr, cS + BR*Hn, xh1, Hn, xh2, tid);
    __syncthreads();

    gemm_mfma<8>(wsw + 2*131072, biasS + 2*G4, xh2, gates, tid);
    __syncthreads();
    activate2(gates, nullptr, cS + 2*BR*Hn, xh2, Hn, (u16*)nullptr, tid);
    __syncthreads();
  }

  // ---------------- decoder: 7 phases per t (was 10) ----------------
  // xh*.h-parts hold enc-final h (written by enc act at t=99); cS carries the
  // enc-final cell state. Only xh0.x must be reset to pred(-1)=0.
  {
    int r = tid >> 7, k = tid & 127;
    if (k < Dn){ xh0[r*RP + k] = 0; xh0[(r+8)*RP + k] = 0; }
  }
  __syncthreads();

  for (int t=0;t<Tn;t++){
    gemm_mfma<6>(wsw + 3*131072, biasS + 3*G4, xh0, gates, tid);
    __syncthreads();
    activate2(gates, nullptr, cS,         xh0, Dn, xh1, tid);
    __syncthreads();

    gemm_mfma<8>(wsw + 4*131072, biasS + 4*G4, xh1, gates, tid);
    __syncthreads();
    activate2(gates, nullptr, cS + BR*Hn, xh1, Hn, xh2, tid);
    __syncthreads();

    gemm_mfma<8>(wsw + 5*131072, biasS + 5*G4, xh2, gates, tid);
    __syncthreads();
    activate2(gates, hS, cS + 2*BR*Hn, xh2, Hn, (u16*)nullptr, tid);
    __syncthreads();

    proj_out(hS, fwtS, fbwS, xh0, out, b0, t, tid);
    __syncthreads();
  }
}

extern "C" void kernel_launch(void* const* d_in, const int* in_sizes, int n_in,
                              void* d_out, int out_size, void* d_ws, size_t ws_size,
                              hipStream_t stream)
{
  (void)in_sizes; (void)n_in; (void)out_size; (void)ws_size;
  const float* src = (const float*)d_in[0];
  WP p;
  for (int l=0;l<3;l++){
    p.W[l]    = (const float*)d_in[1  + 3*l];
    p.U[l]    = (const float*)d_in[2  + 3*l];
    p.Bb[l]   = (const float*)d_in[3  + 3*l];
    p.W[3+l]  = (const float*)d_in[10 + 3*l];
    p.U[3+l]  = (const float*)d_in[11 + 3*l];
    p.Bb[3+l] = (const float*)d_in[12 + 3*l];
  }
  p.fW = (const float*)d_in[19];
  p.fb = (const float*)d_in[20];

  // ws: wsw u16[786432] (1.5MB) | bias f32[3072] | fwt f32[8192] | fbw f32[64]
  u16*   wsw  = (u16*)d_ws;
  float* bias = (float*)((char*)d_ws + 6*131072*sizeof(u16));
  float* fwt  = bias + 6*512;
  float* fbw  = fwt + 8192;

  prep_kernel<<<(PREP_TOTAL + 255)/256, 256, 0, stream>>>(p, wsw, bias, fwt, fbw);
  lstm_kernel<<<NWG, NTH, 0, stream>>>(src, wsw, bias, fwt, fbw, (float*)d_out);
}